// Round 3
// baseline (537.806 us; speedup 1.0000x reference)
//
#include <hip/hip_runtime.h>
#include <stdint.h>

typedef __bf16 bf16x8 __attribute__((ext_vector_type(8)));
typedef float  f32x4  __attribute__((ext_vector_type(4)));

#define BLD   16777216   // 4096*16*256
#define DDIM  256

// ---- LDS map (bytes): params/stats/rowc/const only — NO tile staging ----
#define PARAM_OFF 0        // 8 arrays x 256 f32 (this encoder only) = 8KB
#define STATS_OFF 8192     // 64 rows x 4 waves x 8 f32 = 8KB
#define ROWC_OFF  16384    // 64 rows x 8 f32 = 2KB
#define CONST_OFF 18432    // 4 f32
#define SMEM_BYTES 18448

__device__ __forceinline__ float sigmoid_fast(float x){
  float e = __builtin_amdgcn_exp2f(-1.44269504f * x);
  return __builtin_amdgcn_rcpf(1.0f + e);
}

// load 8 consecutive f32, convert to packed bf16x8 (RNE via compiler fptrunc)
__device__ __forceinline__ bf16x8 cvt8(const float* p){
  float4 a = *(const float4*)p;
  float4 b = *(const float4*)(p + 4);
  bf16x8 r;
  r[0]=(__bf16)a.x; r[1]=(__bf16)a.y; r[2]=(__bf16)a.z; r[3]=(__bf16)a.w;
  r[4]=(__bf16)b.x; r[5]=(__bf16)b.y; r[6]=(__bf16)b.z; r[7]=(__bf16)b.w;
  return r;
}

// param array ids: 0 bg, 1 gng, 2 gnb, 3 bp, 4 png, 5 pnb, 6 wga, 7 wpa
__device__ __forceinline__ float ldp(const unsigned char* sm, int arr, int col){
  return ((const float*)(sm + PARAM_OFF))[arr*256 + col];
}

__global__ __launch_bounds__(256, 2)
void kd_kernel(const float* __restrict__ gfeat, const float* __restrict__ pfeat,
               const float* __restrict__ Wg,  const float* __restrict__ bg,
               const float* __restrict__ gng, const float* __restrict__ gnb,
               const float* __restrict__ Wp,  const float* __restrict__ bp,
               const float* __restrict__ pngm,const float* __restrict__ pnb,
               const float* __restrict__ wga, const float* __restrict__ bga,
               const float* __restrict__ wpa, const float* __restrict__ bpa,
               float* __restrict__ out)
{
  __shared__ __align__(16) unsigned char sm[SMEM_BYTES];
  const int tid  = threadIdx.x;
  const int n    = tid & 15;          // MFMA m/n lane index
  const int q    = (tid >> 4) & 3;    // k-quad / row-quad
  const int w    = tid >> 6;          // wave id: owns cols [64w, 64w+64)
  const int tile = blockIdx.x >> 1;   // 64-row tile
  const int e    = blockIdx.x & 1;    // encoder (paired blocks share feature reads -> L2/L3 hit)

  // ---- stage this encoder's params into LDS (f32), 1 float per thread per array
  {
    float* pp = (float*)(sm + PARAM_OFF);
    pp[0*256 + tid] = bg  [e*256 + tid];
    pp[1*256 + tid] = gng [e*256 + tid];
    pp[2*256 + tid] = gnb [e*256 + tid];
    pp[3*256 + tid] = bp  [e*256 + tid];
    pp[4*256 + tid] = pngm[e*256 + tid];
    pp[5*256 + tid] = pnb [e*256 + tid];
    pp[6*256 + tid] = wga [e*256 + tid];
    pp[7*256 + tid] = wpa [e*256 + tid];
  }
  __syncthreads();

  // ---- dot-fold constants (wave 0): C0=sum(gng*wpa), C1=sum(gnb*wpa),
  //                                   C2=sum(png*wga), C3=sum(pnb*wga)
  if (tid < 64){
    float c0=0.f, c1=0.f, c2=0.f, c3=0.f;
    #pragma unroll
    for (int j = 0; j < 4; ++j){
      int c = tid*4 + j;
      float gng_ = ldp(sm,1,c), gnb_ = ldp(sm,2,c);
      float png_ = ldp(sm,4,c), pnb_ = ldp(sm,5,c);
      float wga_ = ldp(sm,6,c), wpa_ = ldp(sm,7,c);
      c0 += gng_*wpa_; c1 += gnb_*wpa_; c2 += png_*wga_; c3 += pnb_*wga_;
    }
    #pragma unroll
    for (int m = 1; m <= 32; m <<= 1){
      c0 += __shfl_xor(c0,m); c1 += __shfl_xor(c1,m);
      c2 += __shfl_xor(c2,m); c3 += __shfl_xor(c3,m);
    }
    if (tid == 0){
      float* cp = (float*)(sm + CONST_OFF);
      cp[0]=c0; cp[1]=c1; cp[2]=c2; cp[3]=c3;
    }
  }

  // NOTE reference swap: g-GEMM input is pfeat, p-GEMM input is gfeat.
  const float* aGbase = pfeat + (size_t)(tile*64 + n)*DDIM + q*8;
  const float* aPbase = gfeat + (size_t)(tile*64 + n)*DDIM + q*8;

  // ---- acc init = linear bias broadcast (bias folded into GEMM)
  f32x4 accg[4][4], accp[4][4];
  #pragma unroll
  for (int t = 0; t < 4; ++t){
    int col = w*64 + n*4 + t;
    float bgv = ldp(sm,0,col);
    float bpv = ldp(sm,3,col);
    #pragma unroll
    for (int s = 0; s < 4; ++s){
      accg[s][t] = (f32x4){bgv,bgv,bgv,bgv};
      accp[s][t] = (f32x4){bpv,bpv,bpv,bpv};
    }
  }

  // ---- per-lane W row bases: B-frag(t, lane(q,n)) = W[w*64+n*4+t][kk*32+q*8 .. +8]
  // (8 consecutive f32 — exactly what cvt8 loads; no LDS permute needed)
  const float* wgE = Wg + (size_t)e*65536;
  const float* wpE = Wp + (size_t)e*65536;
  const float* wgR[4];
  const float* wpR[4];
  #pragma unroll
  for (int t = 0; t < 4; ++t){
    int row = w*64 + n*4 + t;
    wgR[t] = wgE + (size_t)row*DDIM + q*8;
    wpR[t] = wpE + (size_t)row*DDIM + q*8;
  }

  // ---- K-loop: NO barriers, NO LDS. 32 independent 16B loads + 32 MFMAs per
  // step; compiler pipelines via vmcnt, 2 resident blocks overlap freely.
  for (int kk = 0; kk < 8; ++kk){
    bf16x8 aG[4], aP[4], bG[4], bP[4];
    #pragma unroll
    for (int s = 0; s < 4; ++s){
      aG[s] = cvt8(aGbase + (size_t)s*16*DDIM + kk*32);
      aP[s] = cvt8(aPbase + (size_t)s*16*DDIM + kk*32);
    }
    #pragma unroll
    for (int t = 0; t < 4; ++t){
      bG[t] = cvt8(wgR[t] + kk*32);
      bP[t] = cvt8(wpR[t] + kk*32);
    }
    #pragma unroll
    for (int s = 0; s < 4; ++s){
      #pragma unroll
      for (int t = 0; t < 4; ++t){
        accg[s][t] = __builtin_amdgcn_mfma_f32_16x16x32_bf16(aG[s], bG[t], accg[s][t], 0,0,0);
        accp[s][t] = __builtin_amdgcn_mfma_f32_16x16x32_bf16(aP[s], bP[t], accp[s][t], 0,0,0);
      }
    }
  }

  // ---- epilogue: per-lane per-col params
  float gamg[4], betg[4], gamp[4], betp[4], gwk[4], pwk[4];
  #pragma unroll
  for (int t = 0; t < 4; ++t){
    int col = w*64 + n*4 + t;
    float gng_ = ldp(sm,1,col), gnb_ = ldp(sm,2,col);
    float png_ = ldp(sm,4,col), pnb_ = ldp(sm,5,col);
    float wga_ = ldp(sm,6,col), wpa_ = ldp(sm,7,col);
    gamg[t]=gng_; betg[t]=gnb_; gamp[t]=png_; betp[t]=pnb_;
    gwk[t]=gng_*wpa_;   // weight for sp = dot(g_ln, wpa) fold
    pwk[t]=png_*wga_;   // weight for sg = dot(p_ln, wga) fold
  }

  // stats per row: gs, gq(sum sq), gw(= sum g*gng*wpa), ps, pq, pw(= sum p*png*wga)
  #pragma unroll
  for (int s = 0; s < 4; ++s){
    #pragma unroll
    for (int reg = 0; reg < 4; ++reg){
      float gs=0.f,gq=0.f,gw=0.f,ps=0.f,pq=0.f,pw=0.f;
      #pragma unroll
      for (int t = 0; t < 4; ++t){
        float xg = accg[s][t][reg], xp = accp[s][t][reg];
        gs += xg; gq = fmaf(xg,xg,gq); gw = fmaf(xg,gwk[t],gw);
        ps += xp; pq = fmaf(xp,xp,pq); pw = fmaf(xp,pwk[t],pw);
      }
      #pragma unroll
      for (int m = 1; m <= 8; m <<= 1){
        gs += __shfl_xor(gs,m); gq += __shfl_xor(gq,m); gw += __shfl_xor(gw,m);
        ps += __shfl_xor(ps,m); pq += __shfl_xor(pq,m); pw += __shfl_xor(pw,m);
      }
      if (n == 0){
        int r = s*16 + q*4 + reg;
        float* st = (float*)(sm + STATS_OFF) + (r*4 + w)*8;
        st[0]=gs; st[1]=gq; st[2]=gw; st[3]=ps; st[4]=pq; st[5]=pw;
      }
    }
  }
  __syncthreads();

  if (tid < 64){
    const float* cs = (const float*)(sm + CONST_OFF);
    float gs=0.f,gq=0.f,gw=0.f,ps=0.f,pq=0.f,pw=0.f;
    #pragma unroll
    for (int w2 = 0; w2 < 4; ++w2){
      const float* st = (const float*)(sm + STATS_OFF) + (tid*4 + w2)*8;
      gs+=st[0]; gq+=st[1]; gw+=st[2]; ps+=st[3]; pq+=st[4]; pw+=st[5];
    }
    float mg = gs*(1.f/256.f), vg = fmaxf(gq*(1.f/256.f) - mg*mg, 0.f);
    float rsg = rsqrtf(vg + 1e-5f);
    float mp = ps*(1.f/256.f), vp = fmaxf(pq*(1.f/256.f) - mp*mp, 0.f);
    float rsp = rsqrtf(vp + 1e-5f);
    float sp = rsg*(gw - mg*cs[0]) + cs[1];   // dot(g_ln, wpa)
    float sg = rsp*(pw - mp*cs[2]) + cs[3];   // dot(p_ln, wga)
    float* rc = (float*)(sm + ROWC_OFF) + tid*8;
    rc[0]=mg; rc[1]=rsg; rc[2]=mp; rc[3]=rsp; rc[4]=sg; rc[5]=sp;
  }
  __syncthreads();

  const float bgaf = bga[e];
  const float bpaf = bpa[e];
  #pragma unroll
  for (int s = 0; s < 4; ++s){
    #pragma unroll
    for (int reg = 0; reg < 4; ++reg){
      int r = s*16 + q*4 + reg;
      const float* rc = (const float*)(sm + ROWC_OFF) + r*8;
      float mg=rc[0], rsg=rc[1], mp=rc[2], rsp=rc[3], sg=rc[4], sp=rc[5];
      float4 o;
      float ov[4];
      #pragma unroll
      for (int t = 0; t < 4; ++t){
        float g_ln = fmaf((accg[s][t][reg]-mg)*rsg, gamg[t], betg[t]);
        float p_ln = fmaf((accp[s][t][reg]-mp)*rsp, gamp[t], betp[t]);
        float ga = sigmoid_fast(fmaf(g_ln, sg, bgaf));  // geno_att
        float pa = sigmoid_fast(fmaf(p_ln, sp, bpaf));  // path_att
        ov[t] = p_ln*pa + g_ln*ga;
      }
      o.x = ov[0]; o.y = ov[1]; o.z = ov[2]; o.w = ov[3];
      size_t off = (size_t)e*BLD + ((size_t)tile*64 + r)*DDIM + (w*64 + n*4);
      *(float4*)(out + off) = o;
    }
  }
}

extern "C" void kernel_launch(void* const* d_in, const int* in_sizes, int n_in,
                              void* d_out, int out_size, void* d_ws, size_t ws_size,
                              hipStream_t stream) {
  const float* gfeat = (const float*)d_in[0];
  const float* pfeat = (const float*)d_in[1];
  const float* Wg    = (const float*)d_in[2];
  const float* bg    = (const float*)d_in[3];
  const float* gng   = (const float*)d_in[4];
  const float* gnb   = (const float*)d_in[5];
  const float* Wp    = (const float*)d_in[6];
  const float* bp    = (const float*)d_in[7];
  const float* pngm  = (const float*)d_in[8];
  const float* pnb   = (const float*)d_in[9];
  const float* wga   = (const float*)d_in[10];
  const float* bga   = (const float*)d_in[11];
  const float* wpa   = (const float*)d_in[12];
  const float* bpa   = (const float*)d_in[13];

  dim3 grid(2048), block(256);
  hipLaunchKernelGGL(kd_kernel, grid, block, 0, stream,
                     gfeat, pfeat, Wg, bg, gng, gnb, Wp, bp, pngm, pnb,
                     wga, bga, wpa, bpa, (float*)d_out);
}

// Round 4
// 453.556 us; speedup vs baseline: 1.1858x; 1.1858x over previous
//
#include <hip/hip_runtime.h>
#include <stdint.h>

typedef __bf16 bf16x8 __attribute__((ext_vector_type(8)));
typedef float  f32x4  __attribute__((ext_vector_type(4)));

#define BLD   16777216   // 4096*16*256
#define DDIM  256

// ---- LDS map (bytes) ----
// A slabs: 32 rows x 256 cols bf16 (row stride 512B), XOR-swizzled, per mat.
#define AG_OFF    0        // 16KB
#define AP_OFF    16384    // 16KB
#define PARAM_OFF 32768    // 8 arrays x 256 f32 = 8KB
#define STATS_OFF 40960    // 32 rows x 4 waves x 8 f32 = 4KB
#define ROWC_OFF  45056    // 32 rows x 8 f32 = 1KB
#define CONST_OFF 46080    // 4 f32
#define SMEM_BYTES 46096   // x3 blocks = 138KB <= 160KB/CU

__device__ __forceinline__ float sigmoid_fast(float x){
  float e = __builtin_amdgcn_exp2f(-1.44269504f * x);
  return __builtin_amdgcn_rcpf(1.0f + e);
}

// load 8 consecutive f32, convert to packed bf16x8 (RNE via compiler fptrunc)
__device__ __forceinline__ bf16x8 cvt8(const float* p){
  float4 a = *(const float4*)p;
  float4 b = *(const float4*)(p + 4);
  bf16x8 r;
  r[0]=(__bf16)a.x; r[1]=(__bf16)a.y; r[2]=(__bf16)a.z; r[3]=(__bf16)a.w;
  r[4]=(__bf16)b.x; r[5]=(__bf16)b.y; r[6]=(__bf16)b.z; r[7]=(__bf16)b.w;
  return r;
}

// param array ids: 0 bg, 1 gng, 2 gnb, 3 bp, 4 png, 5 pnb, 6 wga, 7 wpa
__device__ __forceinline__ float ldp(const unsigned char* sm, int arr, int col){
  return ((const float*)(sm + PARAM_OFF))[arr*256 + col];
}

__global__ __launch_bounds__(256, 3)
void kd_kernel(const float* __restrict__ gfeat, const float* __restrict__ pfeat,
               const float* __restrict__ Wg,  const float* __restrict__ bg,
               const float* __restrict__ gng, const float* __restrict__ gnb,
               const float* __restrict__ Wp,  const float* __restrict__ bp,
               const float* __restrict__ pngm,const float* __restrict__ pnb,
               const float* __restrict__ wga, const float* __restrict__ bga,
               const float* __restrict__ wpa, const float* __restrict__ bpa,
               float* __restrict__ out)
{
  __shared__ __align__(16) unsigned char sm[SMEM_BYTES];
  const int tid  = threadIdx.x;
  const int n    = tid & 15;          // MFMA m/n lane index
  const int q    = (tid >> 4) & 3;    // k-quad / row-quad
  const int w    = tid >> 6;          // wave id: owns cols [64w, 64w+64)
  const int tile = blockIdx.x >> 1;   // 32-row tile (0..2047)
  const int e    = blockIdx.x & 1;    // encoder (paired blocks share feature reads -> L2/L3 hit)

  const int q16  = q*16;
  const int xorv = (n & 7) << 4;      // A-LDS swizzle; read row = s*16+n -> row&7 == n&7

  // ---- stage this encoder's params into LDS (f32), 1 float per thread per array
  {
    float* pp = (float*)(sm + PARAM_OFF);
    pp[0*256 + tid] = bg  [e*256 + tid];
    pp[1*256 + tid] = gng [e*256 + tid];
    pp[2*256 + tid] = gnb [e*256 + tid];
    pp[3*256 + tid] = bp  [e*256 + tid];
    pp[4*256 + tid] = pngm[e*256 + tid];
    pp[5*256 + tid] = pnb [e*256 + tid];
    pp[6*256 + tid] = wga [e*256 + tid];
    pp[7*256 + tid] = wpa [e*256 + tid];
  }

  // ---- stage A slabs (both mats) into swizzled bf16 LDS, once per block.
  // Reference swap: g-GEMM input is pfeat, p-GEMM input is gfeat.
  {
    const float* srcG = pfeat + (size_t)tile*32*DDIM;
    const float* srcP = gfeat + (size_t)tile*32*DDIM;
    #pragma unroll
    for (int j = 0; j < 4; ++j){
      int idx = j*2048 + tid*8;       // f32 index into the 32x256 slab
      int row = idx >> 8;
      int col = idx & 255;            // multiple of 8
      bf16x8 vg = cvt8(srcG + idx);
      bf16x8 vp = cvt8(srcP + idx);
      int off = row*512 + ((col*2) ^ ((row & 7) << 4));   // 16B-aligned, bijective
      *(bf16x8*)(sm + AG_OFF + off) = vg;
      *(bf16x8*)(sm + AP_OFF + off) = vp;
    }
  }
  __syncthreads();   // params + A staged; the ONLY barrier before the epilogue

  // ---- dot-fold constants (wave 0): C0=sum(gng*wpa), C1=sum(gnb*wpa),
  //                                   C2=sum(png*wga), C3=sum(pnb*wga)
  if (tid < 64){
    float c0=0.f, c1=0.f, c2=0.f, c3=0.f;
    #pragma unroll
    for (int j = 0; j < 4; ++j){
      int c = tid*4 + j;
      float gng_ = ldp(sm,1,c), gnb_ = ldp(sm,2,c);
      float png_ = ldp(sm,4,c), pnb_ = ldp(sm,5,c);
      float wga_ = ldp(sm,6,c), wpa_ = ldp(sm,7,c);
      c0 += gng_*wpa_; c1 += gnb_*wpa_; c2 += png_*wga_; c3 += pnb_*wga_;
    }
    #pragma unroll
    for (int m = 1; m <= 32; m <<= 1){
      c0 += __shfl_xor(c0,m); c1 += __shfl_xor(c1,m);
      c2 += __shfl_xor(c2,m); c3 += __shfl_xor(c3,m);
    }
    if (tid == 0){
      float* cp = (float*)(sm + CONST_OFF);
      cp[0]=c0; cp[1]=c1; cp[2]=c2; cp[3]=c3;
    }
  }

  // ---- acc init = linear bias broadcast (bias folded into GEMM)
  f32x4 accg[2][4], accp[2][4];
  #pragma unroll
  for (int t = 0; t < 4; ++t){
    int col = w*64 + n*4 + t;
    float bgv = ldp(sm,0,col);
    float bpv = ldp(sm,3,col);
    #pragma unroll
    for (int s = 0; s < 2; ++s){
      accg[s][t] = (f32x4){bgv,bgv,bgv,bgv};
      accp[s][t] = (f32x4){bpv,bpv,bpv,bpv};
    }
  }

  // ---- W addressing: uniform SGPR base + small per-lane int offsets
  // B-frag(t, lane(q,n)) = W[w*64+n*4+t][kk*32+q*8 .. +8]  (8 consecutive f32)
  const float* wgE = Wg + (size_t)e*65536;
  const float* wpE = Wp + (size_t)e*65536;
  int woff[4];
  #pragma unroll
  for (int t = 0; t < 4; ++t)
    woff[t] = (w*64 + n*4 + t)*DDIM + q*8;

  // ---- K-loop: no barriers. Per step: 4 conflict-free ds_read_b128 (A) +
  // 8 cvt8 global loads (W, L2-resident) + 16 MFMA.
  for (int kk = 0; kk < 8; ++kk){
    bf16x8 aG[2], aP[2], bG[4], bP[4];
    #pragma unroll
    for (int s = 0; s < 2; ++s){
      int off = (s*16 + n)*512 + ((kk*64 + q16) ^ xorv);
      aG[s] = *(const bf16x8*)(sm + AG_OFF + off);
      aP[s] = *(const bf16x8*)(sm + AP_OFF + off);
    }
    #pragma unroll
    for (int t = 0; t < 4; ++t){
      bG[t] = cvt8(wgE + woff[t] + kk*32);
      bP[t] = cvt8(wpE + woff[t] + kk*32);
    }
    #pragma unroll
    for (int s = 0; s < 2; ++s){
      #pragma unroll
      for (int t = 0; t < 4; ++t){
        accg[s][t] = __builtin_amdgcn_mfma_f32_16x16x32_bf16(aG[s], bG[t], accg[s][t], 0,0,0);
        accp[s][t] = __builtin_amdgcn_mfma_f32_16x16x32_bf16(aP[s], bP[t], accp[s][t], 0,0,0);
      }
    }
  }

  // ---- epilogue: per-lane per-col params
  float gamg[4], betg[4], gamp[4], betp[4], gwk[4], pwk[4];
  #pragma unroll
  for (int t = 0; t < 4; ++t){
    int col = w*64 + n*4 + t;
    float gng_ = ldp(sm,1,col), gnb_ = ldp(sm,2,col);
    float png_ = ldp(sm,4,col), pnb_ = ldp(sm,5,col);
    float wga_ = ldp(sm,6,col), wpa_ = ldp(sm,7,col);
    gamg[t]=gng_; betg[t]=gnb_; gamp[t]=png_; betp[t]=pnb_;
    gwk[t]=gng_*wpa_;   // weight for sp = dot(g_ln, wpa) fold
    pwk[t]=png_*wga_;   // weight for sg = dot(p_ln, wga) fold
  }

  // stats per row: gs, gq(sum sq), gw(= sum g*gng*wpa), ps, pq, pw(= sum p*png*wga)
  #pragma unroll
  for (int s = 0; s < 2; ++s){
    #pragma unroll
    for (int reg = 0; reg < 4; ++reg){
      float gs=0.f,gq=0.f,gw=0.f,ps=0.f,pq=0.f,pw=0.f;
      #pragma unroll
      for (int t = 0; t < 4; ++t){
        float xg = accg[s][t][reg], xp = accp[s][t][reg];
        gs += xg; gq = fmaf(xg,xg,gq); gw = fmaf(xg,gwk[t],gw);
        ps += xp; pq = fmaf(xp,xp,pq); pw = fmaf(xp,pwk[t],pw);
      }
      #pragma unroll
      for (int m = 1; m <= 8; m <<= 1){
        gs += __shfl_xor(gs,m); gq += __shfl_xor(gq,m); gw += __shfl_xor(gw,m);
        ps += __shfl_xor(ps,m); pq += __shfl_xor(pq,m); pw += __shfl_xor(pw,m);
      }
      if (n == 0){
        int r = s*16 + q*4 + reg;   // 0..31
        float* st = (float*)(sm + STATS_OFF) + (r*4 + w)*8;
        st[0]=gs; st[1]=gq; st[2]=gw; st[3]=ps; st[4]=pq; st[5]=pw;
      }
    }
  }
  __syncthreads();

  if (tid < 32){
    const float* cs = (const float*)(sm + CONST_OFF);
    float gs=0.f,gq=0.f,gw=0.f,ps=0.f,pq=0.f,pw=0.f;
    #pragma unroll
    for (int w2 = 0; w2 < 4; ++w2){
      const float* st = (const float*)(sm + STATS_OFF) + (tid*4 + w2)*8;
      gs+=st[0]; gq+=st[1]; gw+=st[2]; ps+=st[3]; pq+=st[4]; pw+=st[5];
    }
    float mg = gs*(1.f/256.f), vg = fmaxf(gq*(1.f/256.f) - mg*mg, 0.f);
    float rsg = rsqrtf(vg + 1e-5f);
    float mp = ps*(1.f/256.f), vp = fmaxf(pq*(1.f/256.f) - mp*mp, 0.f);
    float rsp = rsqrtf(vp + 1e-5f);
    float sp = rsg*(gw - mg*cs[0]) + cs[1];   // dot(g_ln, wpa)
    float sg = rsp*(pw - mp*cs[2]) + cs[3];   // dot(p_ln, wga)
    float* rc = (float*)(sm + ROWC_OFF) + tid*8;
    rc[0]=mg; rc[1]=rsg; rc[2]=mp; rc[3]=rsp; rc[4]=sg; rc[5]=sp;
  }
  __syncthreads();

  const float bgaf = bga[e];
  const float bpaf = bpa[e];
  #pragma unroll
  for (int s = 0; s < 2; ++s){
    #pragma unroll
    for (int reg = 0; reg < 4; ++reg){
      int r = s*16 + q*4 + reg;
      const float* rc = (const float*)(sm + ROWC_OFF) + r*8;
      float mg=rc[0], rsg=rc[1], mp=rc[2], rsp=rc[3], sg=rc[4], sp=rc[5];
      float4 o;
      float ov[4];
      #pragma unroll
      for (int t = 0; t < 4; ++t){
        float g_ln = fmaf((accg[s][t][reg]-mg)*rsg, gamg[t], betg[t]);
        float p_ln = fmaf((accp[s][t][reg]-mp)*rsp, gamp[t], betp[t]);
        float ga = sigmoid_fast(fmaf(g_ln, sg, bgaf));  // geno_att
        float pa = sigmoid_fast(fmaf(p_ln, sp, bpaf));  // path_att
        ov[t] = p_ln*pa + g_ln*ga;
      }
      o.x = ov[0]; o.y = ov[1]; o.z = ov[2]; o.w = ov[3];
      size_t off = (size_t)e*BLD + ((size_t)tile*32 + r)*DDIM + (w*64 + n*4);
      *(float4*)(out + off) = o;
    }
  }
}

extern "C" void kernel_launch(void* const* d_in, const int* in_sizes, int n_in,
                              void* d_out, int out_size, void* d_ws, size_t ws_size,
                              hipStream_t stream) {
  const float* gfeat = (const float*)d_in[0];
  const float* pfeat = (const float*)d_in[1];
  const float* Wg    = (const float*)d_in[2];
  const float* bg    = (const float*)d_in[3];
  const float* gng   = (const float*)d_in[4];
  const float* gnb   = (const float*)d_in[5];
  const float* Wp    = (const float*)d_in[6];
  const float* bp    = (const float*)d_in[7];
  const float* pngm  = (const float*)d_in[8];
  const float* pnb   = (const float*)d_in[9];
  const float* wga   = (const float*)d_in[10];
  const float* bga   = (const float*)d_in[11];
  const float* wpa   = (const float*)d_in[12];
  const float* bpa   = (const float*)d_in[13];

  dim3 grid(4096), block(256);
  hipLaunchKernelGGL(kd_kernel, grid, block, 0, stream,
                     gfeat, pfeat, Wg, bg, gng, gnb, Wp, bp, pngm, pnb,
                     wga, bga, wpa, bpa, (float*)d_out);
}